// Round 14
// baseline (3290.629 us; speedup 1.0000x reference)
//
#include <hip/hip_runtime.h>

#define DEV __device__ __forceinline__

typedef __attribute__((ext_vector_type(4))) float  f32x4;
typedef __attribute__((ext_vector_type(8))) short  s16x8;   // 8 bf16 (MFMA frag)
typedef __attribute__((ext_vector_type(4))) short  s16x4;   // 4 bf16 (8B ld/st)

union FragU { s16x8 v; unsigned short h[8]; };
union U4    { s16x4 v; unsigned short h[4]; };

DEV float lrelu(float x){ return x > 0.f ? x : 0.2f*x; }
DEV unsigned short bfrne(float f){
    unsigned u = __builtin_bit_cast(unsigned, f);
    u += 0x7fffu + ((u>>16)&1u);
    return (unsigned short)(u>>16);
}
DEV float bf2f(unsigned short h){
    unsigned u = ((unsigned)h)<<16; return __builtin_bit_cast(float,u);
}
DEV f32x4 mfma16(s16x8 a, s16x8 b, f32x4 c){
    return __builtin_amdgcn_mfma_f32_16x16x32_bf16(a, b, c, 0, 0, 0);
}
DEV float wave_sum(float v){
    #pragma unroll
    for(int m=32;m>0;m>>=1) v += __shfl_xor(v, m, 64);
    return v;
}
DEV void blk_reduce2(float& a, float& b, float* sm){
    a = wave_sum(a); b = wave_sum(b);
    int wv = threadIdx.x>>6, ln = threadIdx.x&63;
    if(ln==0){ sm[wv*2]=a; sm[wv*2+1]=b; }
    __syncthreads();
    a = sm[0]+sm[2]+sm[4]+sm[6];
    b = sm[1]+sm[3]+sm[5]+sm[7];
    __syncthreads();
}

// ---------------- sizes ----------------
#define EMB   1048576               // 8*32*4096, one out_emb
#define DKT   111744

// ---------------- init (weights frag-major) + out_embs[0] = in_conv(x) --------
__global__ __launch_bounds__(256) void k_init(
    float* state, float* latout, const float* otlb,
    float* lats, const float* inj,
    unsigned short* w016, const float* c0w,
    unsigned short* w116, const float* c1w,
    unsigned short* wcsh, unsigned short* wcsl, const float* csw,
    const float* x, const float* icw, const float* icb, float* out0)
{
    int i = blockIdx.x*256 + threadIdx.x;
    if(i < 65792){ state[i] = 0.f; return; }            i -= 65792;
    if(i < 4096){ latout[i] = otlb[i&511]; return; }    i -= 4096;
    if(i < 4096){ lats[i] = inj[i]; return; }           i -= 4096;
    if(i < 147456){
        int j = i&7, ln = (i>>3)&63, f2 = i>>9, mt = f2/12, kt = f2 - mt*12;
        w016[i] = bfrne(c0w[(mt*16 + (ln&15))*384 + kt*32 + (ln>>4)*8 + j]);
        return; }                                       i -= 147456;
    if(i < 12288){
        int j = i&7, ln = (i>>3)&63, f2 = i>>9, mt = f2/12, kt = f2 - mt*12;
        w116[i] = bfrne(c1w[(mt*16 + (ln&15))*384 + kt*32 + (ln>>4)*8 + j]);
        return; }                                       i -= 12288;
    if(i < 12288){
        int j = i&7, ln = (i>>3)&63, f2 = i>>9, mt = f2/12, kt = f2 - mt*12;
        wcsh[i] = bfrne(csw[(mt*16 + (ln&15))*384 + kt*32 + (ln>>4)*8 + j]);
        return; }                                       i -= 12288;
    if(i < 12288){
        int j = i&7, ln = (i>>3)&63, f2 = i>>9, mt = f2/12, kt = f2 - mt*12;
        float w = csw[(mt*16 + (ln&15))*384 + kt*32 + (ln>>4)*8 + j];
        unsigned short hh = bfrne(w);
        wcsl[i] = bfrne(w - bf2f(hh)); return; }        i -= 12288;
    if(i < 1048576){
        int p = i & 4095, o = (i>>12)&31, bb = i>>17;
        const float* xb = x + (size_t)bb*12288 + p;
        out0[i] = icb[o] + icw[o*3]*xb[0] + icw[o*3+1]*xb[4096] + icw[o*3+2]*xb[8192];
        return; }
}

// ---------------- latent chain (f32, deterministic; BITWISE-FROZEN values) ----
__global__ __launch_bounds__(256) void k_latA(const float* __restrict__ lat,
    const float* __restrict__ Ws, const float* __restrict__ W0,
    float* __restrict__ ppS, float* __restrict__ ppH)
{
    __shared__ float ls[8][128];
    int t = threadIdx.x;
    int kb = blockIdx.y*128;
    for(int i=t;i<1024;i+=256) ls[i>>7][i&127] = lat[(i>>7)*512 + kb + (i&127)];
    __syncthreads();
    const float* W = blockIdx.z ? W0 : Ws;
    float* pp = blockIdx.z ? ppH : ppS;
    int j = blockIdx.x*128 + (t&127);
    int half = t>>7, klo = half*64;
    int p = blockIdx.y*2 + half;
    float acc[8] = {0,0,0,0,0,0,0,0};
    for(int kk=0;kk<64;kk++){
        float wv_ = W[(size_t)(kb+klo+kk)*512 + j];
        #pragma unroll
        for(int m=0;m<8;m++) acc[m] += ls[m][klo+kk]*wv_;
    }
    #pragma unroll
    for(int m=0;m<8;m++) pp[(size_t)(p*8+m)*512 + j] = acc[m];
}

__global__ __launch_bounds__(256) void k_latBC(const float* __restrict__ ppH,
    const float* __restrict__ flb0c,
    const float* __restrict__ W1, const float* __restrict__ b1c,
    const float* __restrict__ latc, const float* __restrict__ ppS,
    const float* __restrict__ flbsc, float* __restrict__ latn)
{
    __shared__ float lh[8][512];
    __shared__ float part[8][128];
    int t = threadIdx.x;
    for(int i=t;i<4096;i+=256){
        int m = i>>9, jj = i&511;
        float v = flb0c[jj];
        #pragma unroll
        for(int p=0;p<8;p++) v += ppH[(size_t)(p*8+m)*512 + jj];
        lh[m][jj] = lrelu(v);
    }
    __syncthreads();
    int j = blockIdx.x*128 + (t&127), half = t>>7;
    float acc[8] = {0,0,0,0,0,0,0,0};
    int k0 = half*256;
    for(int kk=k0;kk<k0+256;kk++){
        float w = W1[(size_t)kk*512 + j];
        #pragma unroll
        for(int m=0;m<8;m++) acc[m] += lh[m][kk]*w;
    }
    if(half==1){
        #pragma unroll
        for(int m=0;m<8;m++) part[m][t&127] = acc[m];
    }
    __syncthreads();
    if(half==0){
        #pragma unroll
        for(int m=0;m<8;m++){
            float sv = flbsc[j];
            #pragma unroll
            for(int p=0;p<8;p++) sv += ppS[(size_t)(p*8+m)*512 + j];
            float t1 = acc[m] + part[m][t&127] + b1c[j];
            latn[m*512+j] = latc[m*512+j] + 0.1f*sv + 0.01f*t1;
        }
    }
}

// ---------------- DK hidden partials (deterministic; BITWISE-FROZEN) ----------
__global__ __launch_bounds__(256) void k_dkH(const float* __restrict__ latsAll,
    const float* __restrict__ W0, float* __restrict__ ppD)
{
    __shared__ float ls[64][128];
    int t = threadIdx.x;
    int kb = blockIdx.y*128;
    for(int i=t;i<8192;i+=256) ls[i>>7][i&127] = latsAll[(i>>7)*512 + kb + (i&127)];
    __syncthreads();
    int j = blockIdx.x*128 + (t&127);
    int ksub = t>>7;
    int p = blockIdx.y*2 + ksub;
    for(int mc=0;mc<4;mc++){
        float acc[16] = {0,0,0,0,0,0,0,0,0,0,0,0,0,0,0,0};
        for(int kk=0;kk<64;kk++){
            float wv_ = W0[(size_t)(kb + ksub*64 + kk)*1024 + j];
            #pragma unroll
            for(int mi=0;mi<16;mi++) acc[mi] += ls[mc*16+mi][ksub*64+kk]*wv_;
        }
        #pragma unroll
        for(int mi=0;mi<16;mi++) ppD[(size_t)(p*64 + mc*16+mi)*1024 + j] = acc[mi];
    }
}

__global__ __launch_bounds__(256) void k_dkAcvt(const float* __restrict__ latsAll,
    const float* __restrict__ ppD, const float* __restrict__ dkb0,
    unsigned short* __restrict__ Ahi, unsigned short* __restrict__ Alo)
{
    int i = blockIdx.x*256 + threadIdx.x;
    int m = i/1536, k = i - m*1536;
    float v;
    if(k < 512) v = latsAll[m*512 + k];
    else {
        int j = k - 512;
        float hv = dkb0[j];
        #pragma unroll
        for(int p=0;p<8;p++) hv += ppD[(size_t)(p*64+m)*1024 + j];
        v = 0.1f*lrelu(hv);
    }
    unsigned short hh = bfrne(v);
    Ahi[i] = hh; Alo[i] = bfrne(v - bf2f(hh));
}

// ---------------- KS GEMM; epilogue writes FRAG-MAJOR directly ----------------
__global__ __launch_bounds__(256) void k_dkMain(const unsigned short* __restrict__ Ahi,
    const unsigned short* __restrict__ Alo,
    const float* __restrict__ Wsb, const float* __restrict__ W1b,
    const float* __restrict__ bs, const float* __restrict__ b1,
    unsigned short* __restrict__ KSfh, unsigned short* __restrict__ KSfl,
    float* __restrict__ KSb32)
{
    __shared__ unsigned short Wh[64][138];
    __shared__ unsigned short Wl[64][138];
    __shared__ unsigned short Ah[64][72];
    __shared__ unsigned short Al[64][72];
    int t = threadIdx.x, wv = t>>6, lane = t&63, l15 = lane&15, lg = lane>>4, lkb = lg*8;
    int n0 = blockIdx.x*128;
    int sk = t>>5, sc = (t&31)*4;
    int am = t>>2, ac = (t&3)*16;

    f32x4 wreg[8];
    s16x8 ah0, ah1, al0, al1;
    {
        #pragma unroll
        for(int s=0;s<8;s++)
            wreg[s] = *(const f32x4*)(Wsb + (size_t)(sk + s*8)*DKT + n0 + sc);
        const unsigned short* Abh = Ahi + am*1536 + ac;
        const unsigned short* Abl = Alo + am*1536 + ac;
        ah0 = *(const s16x8*)(Abh);     ah1 = *(const s16x8*)(Abh + 8);
        al0 = *(const s16x8*)(Abl);     al1 = *(const s16x8*)(Abl + 8);
    }

    f32x4 acc[4][2];
    #pragma unroll
    for(int mt=0;mt<4;mt++){ acc[mt][0]=f32x4{0,0,0,0}; acc[mt][1]=f32x4{0,0,0,0}; }

    for(int kt=0;kt<24;kt++){
        #pragma unroll
        for(int s=0;s<8;s++){
            int k = sk + s*8;
            unsigned short hh[4], ll[4];
            #pragma unroll
            for(int e=0;e<4;e++){
                float w = wreg[s][e];
                hh[e] = bfrne(w); ll[e] = bfrne(w - bf2f(hh[e]));
            }
            *(unsigned*)(&Wh[k][sc])   = (unsigned)hh[0] | ((unsigned)hh[1]<<16);
            *(unsigned*)(&Wh[k][sc+2]) = (unsigned)hh[2] | ((unsigned)hh[3]<<16);
            *(unsigned*)(&Wl[k][sc])   = (unsigned)ll[0] | ((unsigned)ll[1]<<16);
            *(unsigned*)(&Wl[k][sc+2]) = (unsigned)ll[2] | ((unsigned)ll[3]<<16);
        }
        *(s16x8*)(&Ah[am][ac]) = ah0;  *(s16x8*)(&Ah[am][ac+8]) = ah1;
        *(s16x8*)(&Al[am][ac]) = al0;  *(s16x8*)(&Al[am][ac+8]) = al1;
        __syncthreads();
        if(kt < 23){
            int kn = kt+1;
            const float* Wb = (kn<8) ? (Wsb + (size_t)(kn*64)*DKT)
                                     : (W1b + (size_t)(kn*64-512)*DKT);
            #pragma unroll
            for(int s=0;s<8;s++)
                wreg[s] = *(const f32x4*)(Wb + (size_t)(sk + s*8)*DKT + n0 + sc);
            const unsigned short* Abh = Ahi + am*1536 + kn*64 + ac;
            const unsigned short* Abl = Alo + am*1536 + kn*64 + ac;
            ah0 = *(const s16x8*)(Abh);     ah1 = *(const s16x8*)(Abh + 8);
            al0 = *(const s16x8*)(Abl);     al1 = *(const s16x8*)(Abl + 8);
        }
        #pragma unroll
        for(int ks=0;ks<2;ks++){
            s16x8 afh[4], afl[4];
            #pragma unroll
            for(int mt=0;mt<4;mt++){
                afh[mt] = *(const s16x8*)(&Ah[mt*16+l15][ks*32+lkb]);
                afl[mt] = *(const s16x8*)(&Al[mt*16+l15][ks*32+lkb]);
            }
            #pragma unroll
            for(int nt=0;nt<2;nt++){
                int col = wv*32 + nt*16 + l15;
                FragU bh, bl;
                #pragma unroll
                for(int j=0;j<8;j++){
                    bh.h[j] = Wh[ks*32+lkb+j][col];
                    bl.h[j] = Wl[ks*32+lkb+j][col];
                }
                #pragma unroll
                for(int mt=0;mt<4;mt++){
                    acc[mt][nt] = mfma16(afh[mt], bh.v, acc[mt][nt]);
                    acc[mt][nt] = mfma16(afh[mt], bl.v, acc[mt][nt]);
                    acc[mt][nt] = mfma16(afl[mt], bh.v, acc[mt][nt]);
                }
            }
        }
        __syncthreads();
    }
    // epilogue: write frag-major (bitwise-identical values)
    #pragma unroll
    for(int nt=0;nt<2;nt++){
        int n = n0 + wv*32 + nt*16 + l15;
        float bias = bs[n] + 0.1f*b1[n];
        bool isW = (n < 110592);
        size_t colpart = 0; int nb2 = 0;
        if(isW){
            int L = n / 36864, rem = n - L*36864;
            int g = rem / 9216; int rem2 = rem - g*9216;
            int oo = rem2 / 96; int kk = rem2 - oo*96;
            int lane2 = (((kk&31)>>3)<<4) + (oo&15);
            int f = (oo>>4)*3 + (kk>>5);
            colpart = ((((size_t)(g*3 + L))*18 + f)*64 + lane2)*8 + (kk&7);
        } else nb2 = n - 110592;
        #pragma unroll
        for(int mt=0;mt<4;mt++)
            #pragma unroll
            for(int q=0;q<4;q++){
                int row = mt*16 + lg*4 + q;
                float v = acc[mt][nt][q] + bias;
                unsigned short hh = bfrne(v);
                if(isW){
                    size_t dst = (size_t)row*110592 + colpart;
                    KSfh[dst] = hh;
                    KSfl[dst] = bfrne(v - bf2f(hh));
                } else {
                    KSb32[(size_t)row*1152 + nb2] = v;
                }
            }
    }
}

// ---------------- stats + raw conv dump (BITWISE-FROZEN values) ---------------
__global__ __launch_bounds__(256) void k_stat(const float* __restrict__ outPrev,
    float2* __restrict__ stats, float* __restrict__ gxy)
{
    __shared__ float img[4096], va[4096], vb[4096];
    __shared__ float ct[17], stp[17];
    __shared__ float red[8];
    int t = threadIdx.x, ch = blockIdx.x, b = blockIdx.y;
    const float* src = outPrev + ((size_t)b*32 + ch)*4096;
    float2* stc = stats + (b*32 + ch)*9;
    float* gb = gxy + ((size_t)(b*32 + ch)*8)*4096;
    for(int i=t;i<4096;i+=256) img[i] = src[i];
    __syncthreads();
    float s0=0.f, s1=0.f;
    for(int i=t;i<4096;i+=256){ float v=img[i]; s0+=v; s1+=v*v; }
    blk_reduce2(s0, s1, red);
    float mu = s0*(1.f/4096.f);
    float var = s1*(1.f/4096.f) - mu*mu; var = var<0.f?0.f:var;
    if(t==0) stc[0] = make_float2(mu, rsqrtf(var + 1e-5f));
    const int ksz[4] = {3,5,9,17};
    for(int s=0;s<4;s++){
        int k = ksz[s], p = (k-1)>>1;
        if(t < k){
            float cc = -1.f + 2.f*(float)t/(float)(k-1);
            ct[t]  = cosf(1.5707963267948966f*cc);
            stp[t] = sinf(1.5707963267948966f*cc);
        }
        __syncthreads();
        for(int i=t;i<4096;i+=256){
            int y = i>>6, x = i&63; float ac=0.f, as=0.f;
            for(int tt=0;tt<k;tt++){
                int yy = y+tt-p;
                if(yy>=0 && yy<64){ float f = img[yy*64+x]; ac += ct[tt]*f; as += stp[tt]*f; }
            }
            va[i]=ac; vb[i]=as;
        }
        __syncthreads();
        float gx0=0.f,gx1=0.f,gy0=0.f,gy1=0.f;
        float* g0 = gb + (size_t)(2*s)*4096;
        float* g1 = gb + (size_t)(2*s+1)*4096;
        for(int i=t;i<4096;i+=256){
            int y=i>>6, x=i&63; float gx=0.f, gy=0.f;
            for(int tt=0;tt<k;tt++){
                int xx = x+tt-p;
                if(xx>=0 && xx<64){ gx += stp[tt]*va[y*64+xx]; gy += ct[tt]*vb[y*64+xx]; }
            }
            g0[i] = gx; g1[i] = gy;
            gx0+=gx; gx1+=gx*gx; gy0+=gy; gy1+=gy*gy;
        }
        blk_reduce2(gx0, gx1, red);
        blk_reduce2(gy0, gy1, red);
        float mgx = gx0*(1.f/4096.f), vgx = gx1*(1.f/4096.f)-mgx*mgx; vgx=vgx<0.f?0.f:vgx;
        float mgy = gy0*(1.f/4096.f), vgy = gy1*(1.f/4096.f)-mgy*mgy; vgy=vgy<0.f?0.f:vgy;
        if(t==0){
            stc[1+2*s] = make_float2(mgx, rsqrtf(vgx+1e-5f));
            stc[2+2*s] = make_float2(mgy, rsqrtf(vgy+1e-5f));
        }
        __syncthreads();
    }
}

// ---------------- MEGA v5: ch-octet-major z LDS ------------------------------
__global__ __launch_bounds__(512) void k_mega(const float* __restrict__ outPrev,
    const float2* __restrict__ stats, const float* __restrict__ gxy,
    const unsigned short* __restrict__ KSfh, const unsigned short* __restrict__ KSfl,
    const float* __restrict__ KSb32,
    const unsigned short* __restrict__ w016, const unsigned short* __restrict__ w116,
    const unsigned short* __restrict__ wcsh, const unsigned short* __restrict__ wcsl,
    const float* __restrict__ c0b, const float* __restrict__ c1b,
    const float* __restrict__ csb,
    float* __restrict__ outNext, int cCall)
{
    __shared__ __align__(16) unsigned short zth[12][4][64][8];   // 48 KB
    __shared__ __align__(16) unsigned short ztl[12][4][64][8];   // 48 KB
    __shared__ __align__(16) unsigned short lhf[25600];          // 50 KB
    __shared__ float2 sst[288];
    int t = threadIdx.x, x = t&63, cq = t>>6;     // cq = wave 0..7
    int y = blockIdx.x, b = blockIdx.y;
    const float* ob = outPrev + (size_t)b*131072;
    for(int i=t;i<288;i+=512) sst[i] = stats[b*288 + i];
    __syncthreads();
    int qh = cq>>1, qo = (cq&1)*4;
    {
        U4 idh, idl;
        #pragma unroll
        for(int i=0;i<4;i++){
            int ch = cq*4 + i;
            float v = ob[(size_t)ch*4096 + y*64 + x];
            float2 sr = sst[ch*9];
            float z = (v - sr.x)*sr.y;
            idh.h[i] = bfrne(z); idl.h[i] = bfrne(z - bf2f(idh.h[i]));
        }
        #pragma unroll
        for(int s=0;s<4;s++){
            *(s16x4*)(&zth[3*s][qh][x][qo]) = idh.v;
            *(s16x4*)(&ztl[3*s][qh][x][qo]) = idl.v;
        }
    }
    #pragma unroll 1
    for(int s=0;s<4;s++){
        U4 xh, xl, yh, yl;
        #pragma unroll
        for(int i=0;i<4;i++){
            int ch = cq*4 + i;
            const float* gsrc = gxy + ((size_t)(b*32 + ch)*8)*4096 + y*64 + x;
            float gx = gsrc[(size_t)(2*s)*4096];
            float gy = gsrc[(size_t)(2*s+1)*4096];
            float2 sx = sst[ch*9 + 1+2*s], sy = sst[ch*9 + 2+2*s];
            float zx = (gx - sx.x)*sx.y, zy = (gy - sy.x)*sy.y;
            xh.h[i] = bfrne(zx); xl.h[i] = bfrne(zx - bf2f(xh.h[i]));
            yh.h[i] = bfrne(zy); yl.h[i] = bfrne(zy - bf2f(yh.h[i]));
        }
        *(s16x4*)(&zth[3*s+1][qh][x][qo]) = xh.v;
        *(s16x4*)(&ztl[3*s+1][qh][x][qo]) = xl.v;
        *(s16x4*)(&zth[3*s+2][qh][x][qo]) = yh.v;
        *(s16x4*)(&ztl[3*s+2][qh][x][qo]) = yl.v;
    }
    __syncthreads();

    int lane = t&63, l15 = lane&15, lg = lane>>4, lkb = lg*8, w = cq;
    int pxslot = w&3, half = w>>2;
    int row = cCall*8 + b;
    int pxl = pxslot*16 + l15;
    unsigned short* lhh = &lhf[w*3200];
    unsigned short* lhl = &lhf[w*3200 + 1600];
    #pragma unroll 1
    for(int gi=0; gi<2; gi++){
        int g = half*2 + gi;
        const unsigned short* Kfh = KSfh + (size_t)((row*4 + g)*3)*9216;
        const unsigned short* Kfl = KSfl + (size_t)((row*4 + g)*3)*9216;
        const float* Bf = KSb32 + (size_t)row*1152 + g*96;

        f32x4 acc[6];
        #pragma unroll
        for(int mt=0;mt<6;mt++) acc[mt]=f32x4{0,0,0,0};
        #pragma unroll
        for(int kt=0;kt<3;kt++){
            s16x8 bh = *(const s16x8*)(&zth[g*3+kt][lg][pxl][0]);
            s16x8 bl = *(const s16x8*)(&ztl[g*3+kt][lg][pxl][0]);
            #pragma unroll
            for(int mt=0;mt<6;mt++){
                s16x8 ah = *(const s16x8*)(Kfh + ((mt*3+kt)*64 + lane)*8);
                s16x8 al = *(const s16x8*)(Kfl + ((mt*3+kt)*64 + lane)*8);
                acc[mt] = mfma16(ah, bh, acc[mt]);
                acc[mt] = mfma16(ah, bl, acc[mt]);
                acc[mt] = mfma16(al, bh, acc[mt]);
            }
        }
        #pragma unroll
        for(int mt=0;mt<6;mt++){
            int o0 = mt*16 + lg*4;
            f32x4 bb = *(const f32x4*)(Bf + o0);
            U4 hh, hl;
            #pragma unroll
            for(int q=0;q<4;q++){
                float v = lrelu(acc[mt][q] + bb[q]);
                hh.h[q] = bfrne(v); hl.h[q] = bfrne(v - bf2f(hh.h[q]));
            }
            *(s16x4*)(&lhh[l15*100 + o0]) = hh.v;
            *(s16x4*)(&lhl[l15*100 + o0]) = hl.v;
        }
        #pragma unroll
        for(int mt=0;mt<6;mt++) acc[mt]=f32x4{0,0,0,0};
        #pragma unroll
        for(int kt=0;kt<3;kt++){
            s16x8 bh = *(const s16x8*)(&lhh[l15*100 + kt*32+lkb]);
            s16x8 bl = *(const s16x8*)(&lhl[l15*100 + kt*32+lkb]);
            #pragma unroll
            for(int mt=0;mt<6;mt++){
                s16x8 ah = *(const s16x8*)(Kfh + 9216 + ((mt*3+kt)*64 + lane)*8);
                s16x8 al = *(const s16x8*)(Kfl + 9216 + ((mt*3+kt)*64 + lane)*8);
                acc[mt] = mfma16(ah, bh, acc[mt]);
                acc[mt] = mfma16(ah, bl, acc[mt]);
                acc[mt] = mfma16(al, bh, acc[mt]);
            }
        }
        #pragma unroll
        for(int mt=0;mt<6;mt++){
            int o0 = mt*16 + lg*4;
            f32x4 bb = *(const f32x4*)(Bf + 384 + o0);
            U4 hh, hl;
            #pragma unroll
            for(int q=0;q<4;q++){
                float v = lrelu(acc[mt][q] + bb[q]);
                hh.h[q] = bfrne(v); hl.h[q] = bfrne(v - bf2f(hh.h[q]));
            }
            *(s16x4*)(&lhh[l15*100 + o0]) = hh.v;
            *(s16x4*)(&lhl[l15*100 + o0]) = hl.v;
        }
        #pragma unroll
        for(int mt=0;mt<6;mt++) acc[mt]=f32x4{0,0,0,0};
        #pragma unroll
        for(int kt=0;kt<3;kt++){
            s16x8 bh = *(const s16x8*)(&lhh[l15*100 + kt*32+lkb]);
            s16x8 bl = *(const s16x8*)(&lhl[l15*100 + kt*32+lkb]);
            #pragma unroll
            for(int mt=0;mt<6;mt++){
                s16x8 ah = *(const s16x8*)(Kfh + 18432 + ((mt*3+kt)*64 + lane)*8);
                s16x8 al = *(const s16x8*)(Kfl + 18432 + ((mt*3+kt)*64 + lane)*8);
                acc[mt] = mfma16(ah, bh, acc[mt]);
                acc[mt] = mfma16(ah, bl, acc[mt]);
                acc[mt] = mfma16(al, bh, acc[mt]);
            }
        }
        #pragma unroll
        for(int mt=0;mt<6;mt++){
            int o0 = mt*16 + lg*4;
            f32x4 bb = *(const f32x4*)(Bf + 768 + o0);
            int part = g*3 + (o0>>5), cc = o0&31;
            int q8 = cc>>3, off = cc&7;
            U4 zvh, zvl;
            zvh.v = *(const s16x4*)(&zth[part][q8][pxl][off]);
            zvl.v = *(const s16x4*)(&ztl[part][q8][pxl][off]);
            U4 ozh;
            #pragma unroll
            for(int q=0;q<4;q++){
                float zf = bf2f(zvh.h[q]) + bf2f(zvl.h[q]);
                float d  = zf + acc[mt][q] + bb[q];
                float sg = 1.f/(1.f + __expf(-d));
                ozh.h[q] = bfrne(zf*sg);
            }
            *(s16x4*)(&zth[part][q8][pxl][off]) = ozh.v;
        }
    }
    __syncthreads();

    unsigned short* ldx = &lhf[pxslot*6272];
    f32x4 a1[12];
    #pragma unroll
    for(int lm=0;lm<12;lm++) a1[lm]=f32x4{0,0,0,0};
    #pragma unroll 1
    for(int kt=0;kt<12;kt++){
        FragU bzh, blz;
        bzh.v = *(const s16x8*)(&zth[kt][lg][pxl][0]);
        #pragma unroll
        for(int j=0;j<8;j++) blz.h[j] = bfrne(lrelu(bf2f(bzh.h[j])));
        #pragma unroll
        for(int lm=0;lm<12;lm++){
            int mt = half*12 + lm;
            s16x8 af = *(const s16x8*)(w016 + ((size_t)(mt*12+kt)<<9) + (lane<<3));
            a1[lm] = mfma16(af, blz.v, a1[lm]);
        }
    }
    #pragma unroll
    for(int lm=0;lm<12;lm++){
        int mt = half*12 + lm;
        int o0 = mt*16 + lg*4;
        f32x4 bb = *(const f32x4*)(c0b + o0);
        U4 hv;
        #pragma unroll
        for(int q=0;q<4;q++) hv.h[q] = bfrne(lrelu(a1[lm][q] + bb[q]));
        *(s16x4*)(&ldx[l15*392 + o0]) = hv.v;
    }
    __syncthreads();

    {
        int mt = half;
        f32x4 a2 = f32x4{0,0,0,0};
        f32x4 a3 = f32x4{0,0,0,0};
        #pragma unroll 1
        for(int kt=0;kt<12;kt++){
            s16x8 bh_ = *(const s16x8*)(&ldx[l15*392 + kt*32 + lkb]);
            s16x8 bzh = *(const s16x8*)(&zth[kt][lg][pxl][0]);
            s16x8 af1 = *(const s16x8*)(w116 + ((size_t)(mt*12+kt)<<9) + (lane<<3));
            a2 = mfma16(af1, bh_, a2);
            s16x8 wh = *(const s16x8*)(wcsh + ((size_t)(mt*12+kt)<<9) + (lane<<3));
            s16x8 wl = *(const s16x8*)(wcsl + ((size_t)(mt*12+kt)<<9) + (lane<<3));
            a3 = mfma16(wh, bzh, a3);
            a3 = mfma16(wl, bzh, a3);
        }
        int o0 = mt*16 + lg*4;
        #pragma unroll
        for(int q=0;q<4;q++){
            int o = o0+q;
            int px = y*64 + pxl;
            float dx2 = a2[q] + c1b[o];
            float r   = a3[q] + csb[o] + 0.1f*dx2;
            size_t oidx = (size_t)b*131072 + (size_t)o*4096 + px;
            outNext[oidx] = outPrev[oidx] + 0.1f*r;
        }
    }
}

// ---------------- head ----------------
__global__ __launch_bounds__(256) void k_head1(const float* __restrict__ outF,
    const float* __restrict__ wout, const float* __restrict__ bout, float* __restrict__ state)
{
    __shared__ float sw[97*32];
    __shared__ float sb_[97];
    __shared__ float fp[32];
    __shared__ float fwp[2048];
    int t = threadIdx.x, b = blockIdx.y, pxb = blockIdx.x*256;
    for(int i=t;i<97*32;i+=256) sw[i] = wout[i];
    if(t<97) sb_[t] = bout[t];
    if(t<32) fp[t] = 0.f;
    for(int i=t;i<2048;i+=256) fwp[i] = 0.f;
    __syncthreads();
    int px = pxb + t, lane = t&63, wv = t>>6;
    float xi[32];
    #pragma unroll
    for(int i=0;i<32;i++) xi[i] = outF[(size_t)b*131072 + (size_t)i*4096 + px];
    float* st = state + (size_t)b*8224;
    int row = (pxb>>6) + wv, x = lane;
    for(int o=0;o<97;o++){
        float acc = sb_[o];
        #pragma unroll
        for(int i=0;i<32;i++) acc += sw[o*32+i]*xi[i];
        if(o < 32){
            float s = wave_sum(acc);
            if(lane==0) atomicAdd(&fp[o], s);
        } else if(o < 64){
            float s = wave_sum(acc);
            if(lane==0) st[32 + (o-32)*64 + row] = s*(1.f/64.f);
        } else if(o < 96){
            atomicAdd(&fwp[(o-64)*64 + x], acc);
        } else {
            st[4128 + px] = acc;
        }
    }
    __syncthreads();
    if(t<32) atomicAdd(&st[t], fp[t]*(1.f/4096.f));
    for(int i=t;i<2048;i+=256) atomicAdd(&st[2080+i], fwp[i]*(1.f/64.f));
}

__global__ __launch_bounds__(256) void k_head2(const float* __restrict__ state,
    const float* __restrict__ otlw, float* __restrict__ latout)
{
    __shared__ float ss[8*514];
    int t = threadIdx.x, j = blockIdx.x*256 + t, s0 = blockIdx.y*514;
    for(int i=t;i<8*514;i+=256){ int bb=i/514, si=i-bb*514; ss[i] = state[(size_t)bb*8224 + s0 + si]; }
    __syncthreads();
    float acc[8] = {0,0,0,0,0,0,0,0};
    for(int si=0;si<514;si++){
        float wv_ = otlw[(size_t)(s0+si)*512 + j];
        #pragma unroll
        for(int b2=0;b2<8;b2++) acc[b2] += ss[b2*514+si]*wv_;
    }
    #pragma unroll
    for(int b2=0;b2<8;b2++) atomicAdd(latout + b2*512 + j, acc[b2]);
}

// =============================================================================
extern "C" void kernel_launch(void* const* d_in, const int* in_sizes, int n_in,
                              void* d_out, int out_size, void* d_ws, size_t ws_size,
                              hipStream_t stream)
{
    const float* x    = (const float*)d_in[0];
    const float* inj  = (const float*)d_in[1];
    const float* icw  = (const float*)d_in[2];
    const float* icb  = (const float*)d_in[3];
    const float* flWs = (const float*)d_in[4];
    const float* flbs = (const float*)d_in[5];
    const float* flW0 = (const float*)d_in[6];
    const float* flb0 = (const float*)d_in[7];
    const float* flW1 = (const float*)d_in[8];
    const float* flb1 = (const float*)d_in[9];
    const float* dkWs = (const float*)d_in[10];
    const float* dkbs = (const float*)d_in[11];
    const float* dkW0 = (const float*)d_in[12];
    const float* dkb0 = (const float*)d_in[13];
    const float* dkW1 = (const float*)d_in[14];
    const float* dkb1 = (const float*)d_in[15];
    const float* c0w  = (const float*)d_in[16];
    const float* c0b  = (const float*)d_in[17];
    const float* c1w  = (const float*)d_in[18];
    const float* c1b  = (const float*)d_in[19];
    const float* csw  = (const float*)d_in[20];
    const float* csb  = (const float*)d_in[21];
    const float* ocw  = (const float*)d_in[22];
    const float* ocb  = (const float*)d_in[23];
    const float* otlw = (const float*)d_in[24];
    const float* otlb = (const float*)d_in[25];
    float* out = (float*)d_out;

    char* wp = (char*)d_ws;
    auto carve = [&](size_t bytes)->void*{ void* p = wp; wp += (bytes + 255) & ~(size_t)255; return p; };
    float* lats  = (float*)carve(36864*4);
    float* ppS   = (float*)carve(32768*4);
    float* ppH   = (float*)carve(32768*4);
    float* ppD   = (float*)carve(524288*4);
    float* state = (float*)carve(65792*4);
    float2* stats = (float2*)carve(2304*8);
    float* gxy   = (float*)carve((size_t)8388608*4);
    unsigned short* Ahi   = (unsigned short*)carve((size_t)98304*2);
    unsigned short* Alo   = (unsigned short*)carve((size_t)98304*2);
    unsigned short* KSfh  = (unsigned short*)carve((size_t)7077888*2);
    unsigned short* KSfl  = (unsigned short*)carve((size_t)7077888*2);
    float*          KSb32 = (float*)carve((size_t)73728*4);
    unsigned short* w016  = (unsigned short*)carve((size_t)147456*2);
    unsigned short* w116  = (unsigned short*)carve((size_t)12288*2);
    unsigned short* wcsh  = (unsigned short*)carve((size_t)12288*2);
    unsigned short* wcsl  = (unsigned short*)carve((size_t)12288*2);
    float* outDummy = (float*)carve((size_t)EMB*4);    // DIAGNOSTIC scratch

    k_init<<<5105,256,0,stream>>>(state, out, otlb, lats, inj,
                                  w016, c0w, w116, c1w, wcsh, wcsl, csw,
                                  x, icw, icb, out + 4096);

    for(int c=0;c<8;c++){
        const float* latc = lats + c*4096;
        k_latA<<<dim3(4,4,2),256,0,stream>>>(latc, flWs + (size_t)c*262144, flW0 + (size_t)c*262144,
                                             ppS, ppH);
        k_latBC<<<4,256,0,stream>>>(ppH, flb0 + (size_t)c*512,
                                    flW1 + (size_t)c*262144, flb1 + (size_t)c*512,
                                    latc, ppS, flbs + (size_t)c*512, lats + (c+1)*4096);
    }

    k_dkH<<<dim3(8,4),256,0,stream>>>(lats + 4096, dkW0, ppD);
    k_dkAcvt<<<384,256,0,stream>>>(lats + 4096, ppD, dkb0, Ahi, Alo);
    k_dkMain<<<873,256,0,stream>>>(Ahi, Alo, dkWs, dkW1, dkbs, dkb1, KSfh, KSfl, KSb32);

    for(int c=0;c<8;c++){
        const float* outPrev = out + 4096 + (size_t)c*EMB;
        float*       outNext = out + 4096 + (size_t)(c+1)*EMB;
        k_stat<<<dim3(32,8),256,0,stream>>>(outPrev, stats, gxy);
        k_mega<<<dim3(64,8),512,0,stream>>>(outPrev, stats, gxy, KSfh, KSfl, KSb32,
                                            w016, w116, wcsh, wcsl,
                                            c0b, c1b, csb, outNext, c);
        // DIAGNOSTIC duplicate: identical inputs, scratch output. dur delta = 8*T_mega.
        k_mega<<<dim3(64,8),512,0,stream>>>(outPrev, stats, gxy, KSfh, KSfl, KSb32,
                                            w016, w116, wcsh, wcsl,
                                            c0b, c1b, csb, outDummy, c);
    }

    k_head1<<<dim3(16,8),256,0,stream>>>(out + 4096 + (size_t)8*EMB, ocw, ocb, state);
    k_head2<<<dim3(2,16),256,0,stream>>>(state, otlw, out);
}

// Round 15
// 2080.146 us; speedup vs baseline: 1.5819x; 1.5819x over previous
//
#include <hip/hip_runtime.h>

#define DEV __device__ __forceinline__

typedef __attribute__((ext_vector_type(4))) float  f32x4;
typedef __attribute__((ext_vector_type(8))) short  s16x8;   // 8 bf16 (MFMA frag)
typedef __attribute__((ext_vector_type(4))) short  s16x4;   // 4 bf16 (8B ld/st)

union FragU { s16x8 v; unsigned short h[8]; };
union U4    { s16x4 v; unsigned short h[4]; };

DEV float lrelu(float x){ return x > 0.f ? x : 0.2f*x; }
DEV unsigned short bfrne(float f){
    unsigned u = __builtin_bit_cast(unsigned, f);
    u += 0x7fffu + ((u>>16)&1u);
    return (unsigned short)(u>>16);
}
DEV float bf2f(unsigned short h){
    unsigned u = ((unsigned)h)<<16; return __builtin_bit_cast(float,u);
}
DEV f32x4 mfma16(s16x8 a, s16x8 b, f32x4 c){
    return __builtin_amdgcn_mfma_f32_16x16x32_bf16(a, b, c, 0, 0, 0);
}
DEV float wave_sum(float v){
    #pragma unroll
    for(int m=32;m>0;m>>=1) v += __shfl_xor(v, m, 64);
    return v;
}
DEV void blk_reduce2(float& a, float& b, float* sm){
    a = wave_sum(a); b = wave_sum(b);
    int wv = threadIdx.x>>6, ln = threadIdx.x&63;
    if(ln==0){ sm[wv*2]=a; sm[wv*2+1]=b; }
    __syncthreads();
    a = sm[0]+sm[2]+sm[4]+sm[6];
    b = sm[1]+sm[3]+sm[5]+sm[7];
    __syncthreads();
}

// ---------------- sizes ----------------
#define EMB   1048576               // 8*32*4096, one out_emb
#define DKT   111744

// ---------------- init (weights frag-major) + out_embs[0] = in_conv(x) --------
__global__ __launch_bounds__(256) void k_init(
    float* state, float* latout, const float* otlb,
    float* lats, const float* inj,
    unsigned short* w016, const float* c0w,
    unsigned short* w116, const float* c1w,
    unsigned short* wcsh, unsigned short* wcsl, const float* csw,
    const float* x, const float* icw, const float* icb, float* out0)
{
    int i = blockIdx.x*256 + threadIdx.x;
    if(i < 65792){ state[i] = 0.f; return; }            i -= 65792;
    if(i < 4096){ latout[i] = otlb[i&511]; return; }    i -= 4096;
    if(i < 4096){ lats[i] = inj[i]; return; }           i -= 4096;
    if(i < 147456){
        int j = i&7, ln = (i>>3)&63, f2 = i>>9, mt = f2/12, kt = f2 - mt*12;
        w016[i] = bfrne(c0w[(mt*16 + (ln&15))*384 + kt*32 + (ln>>4)*8 + j]);
        return; }                                       i -= 147456;
    if(i < 12288){
        int j = i&7, ln = (i>>3)&63, f2 = i>>9, mt = f2/12, kt = f2 - mt*12;
        w116[i] = bfrne(c1w[(mt*16 + (ln&15))*384 + kt*32 + (ln>>4)*8 + j]);
        return; }                                       i -= 12288;
    if(i < 12288){
        int j = i&7, ln = (i>>3)&63, f2 = i>>9, mt = f2/12, kt = f2 - mt*12;
        wcsh[i] = bfrne(csw[(mt*16 + (ln&15))*384 + kt*32 + (ln>>4)*8 + j]);
        return; }                                       i -= 12288;
    if(i < 12288){
        int j = i&7, ln = (i>>3)&63, f2 = i>>9, mt = f2/12, kt = f2 - mt*12;
        float w = csw[(mt*16 + (ln&15))*384 + kt*32 + (ln>>4)*8 + j];
        unsigned short hh = bfrne(w);
        wcsl[i] = bfrne(w - bf2f(hh)); return; }        i -= 12288;
    if(i < 1048576){
        int p = i & 4095, o = (i>>12)&31, bb = i>>17;
        const float* xb = x + (size_t)bb*12288 + p;
        out0[i] = icb[o] + icw[o*3]*xb[0] + icw[o*3+1]*xb[4096] + icw[o*3+2]*xb[8192];
        return; }
}

// ---------------- latent chain (f32, deterministic; BITWISE-FROZEN values) ----
__global__ __launch_bounds__(256) void k_latA(const float* __restrict__ lat,
    const float* __restrict__ Ws, const float* __restrict__ W0,
    float* __restrict__ ppS, float* __restrict__ ppH)
{
    __shared__ float ls[8][128];
    int t = threadIdx.x;
    int kb = blockIdx.y*128;
    for(int i=t;i<1024;i+=256) ls[i>>7][i&127] = lat[(i>>7)*512 + kb + (i&127)];
    __syncthreads();
    const float* W = blockIdx.z ? W0 : Ws;
    float* pp = blockIdx.z ? ppH : ppS;
    int j = blockIdx.x*128 + (t&127);
    int half = t>>7, klo = half*64;
    int p = blockIdx.y*2 + half;
    float acc[8] = {0,0,0,0,0,0,0,0};
    for(int kk=0;kk<64;kk++){
        float wv_ = W[(size_t)(kb+klo+kk)*512 + j];
        #pragma unroll
        for(int m=0;m<8;m++) acc[m] += ls[m][klo+kk]*wv_;
    }
    #pragma unroll
    for(int m=0;m<8;m++) pp[(size_t)(p*8+m)*512 + j] = acc[m];
}

__global__ __launch_bounds__(256) void k_latBC(const float* __restrict__ ppH,
    const float* __restrict__ flb0c,
    const float* __restrict__ W1, const float* __restrict__ b1c,
    const float* __restrict__ latc, const float* __restrict__ ppS,
    const float* __restrict__ flbsc, float* __restrict__ latn)
{
    __shared__ float lh[8][512];
    __shared__ float part[8][128];
    int t = threadIdx.x;
    for(int i=t;i<4096;i+=256){
        int m = i>>9, jj = i&511;
        float v = flb0c[jj];
        #pragma unroll
        for(int p=0;p<8;p++) v += ppH[(size_t)(p*8+m)*512 + jj];
        lh[m][jj] = lrelu(v);
    }
    __syncthreads();
    int j = blockIdx.x*128 + (t&127), half = t>>7;
    float acc[8] = {0,0,0,0,0,0,0,0};
    int k0 = half*256;
    for(int kk=k0;kk<k0+256;kk++){
        float w = W1[(size_t)kk*512 + j];
        #pragma unroll
        for(int m=0;m<8;m++) acc[m] += lh[m][kk]*w;
    }
    if(half==1){
        #pragma unroll
        for(int m=0;m<8;m++) part[m][t&127] = acc[m];
    }
    __syncthreads();
    if(half==0){
        #pragma unroll
        for(int m=0;m<8;m++){
            float sv = flbsc[j];
            #pragma unroll
            for(int p=0;p<8;p++) sv += ppS[(size_t)(p*8+m)*512 + j];
            float t1 = acc[m] + part[m][t&127] + b1c[j];
            latn[m*512+j] = latc[m*512+j] + 0.1f*sv + 0.01f*t1;
        }
    }
}

// ---------------- DK hidden partials (deterministic; BITWISE-FROZEN) ----------
__global__ __launch_bounds__(256) void k_dkH(const float* __restrict__ latsAll,
    const float* __restrict__ W0, float* __restrict__ ppD)
{
    __shared__ float ls[64][128];
    int t = threadIdx.x;
    int kb = blockIdx.y*128;
    for(int i=t;i<8192;i+=256) ls[i>>7][i&127] = latsAll[(i>>7)*512 + kb + (i&127)];
    __syncthreads();
    int j = blockIdx.x*128 + (t&127);
    int ksub = t>>7;
    int p = blockIdx.y*2 + ksub;
    for(int mc=0;mc<4;mc++){
        float acc[16] = {0,0,0,0,0,0,0,0,0,0,0,0,0,0,0,0};
        for(int kk=0;kk<64;kk++){
            float wv_ = W0[(size_t)(kb + ksub*64 + kk)*1024 + j];
            #pragma unroll
            for(int mi=0;mi<16;mi++) acc[mi] += ls[mc*16+mi][ksub*64+kk]*wv_;
        }
        #pragma unroll
        for(int mi=0;mi<16;mi++) ppD[(size_t)(p*64 + mc*16+mi)*1024 + j] = acc[mi];
    }
}

__global__ __launch_bounds__(256) void k_dkAcvt(const float* __restrict__ latsAll,
    const float* __restrict__ ppD, const float* __restrict__ dkb0,
    unsigned short* __restrict__ Ahi, unsigned short* __restrict__ Alo)
{
    int i = blockIdx.x*256 + threadIdx.x;
    int m = i/1536, k = i - m*1536;
    float v;
    if(k < 512) v = latsAll[m*512 + k];
    else {
        int j = k - 512;
        float hv = dkb0[j];
        #pragma unroll
        for(int p=0;p<8;p++) hv += ppD[(size_t)(p*64+m)*1024 + j];
        v = 0.1f*lrelu(hv);
    }
    unsigned short hh = bfrne(v);
    Ahi[i] = hh; Alo[i] = bfrne(v - bf2f(hh));
}

// ---------------- KS GEMM; epilogue writes FRAG-MAJOR directly ----------------
__global__ __launch_bounds__(256) void k_dkMain(const unsigned short* __restrict__ Ahi,
    const unsigned short* __restrict__ Alo,
    const float* __restrict__ Wsb, const float* __restrict__ W1b,
    const float* __restrict__ bs, const float* __restrict__ b1,
    unsigned short* __restrict__ KSfh, unsigned short* __restrict__ KSfl,
    float* __restrict__ KSb32)
{
    __shared__ unsigned short Wh[64][138];
    __shared__ unsigned short Wl[64][138];
    __shared__ unsigned short Ah[64][72];
    __shared__ unsigned short Al[64][72];
    int t = threadIdx.x, wv = t>>6, lane = t&63, l15 = lane&15, lg = lane>>4, lkb = lg*8;
    int n0 = blockIdx.x*128;
    int sk = t>>5, sc = (t&31)*4;
    int am = t>>2, ac = (t&3)*16;

    f32x4 wreg[8];
    s16x8 ah0, ah1, al0, al1;
    {
        #pragma unroll
        for(int s=0;s<8;s++)
            wreg[s] = *(const f32x4*)(Wsb + (size_t)(sk + s*8)*DKT + n0 + sc);
        const unsigned short* Abh = Ahi + am*1536 + ac;
        const unsigned short* Abl = Alo + am*1536 + ac;
        ah0 = *(const s16x8*)(Abh);     ah1 = *(const s16x8*)(Abh + 8);
        al0 = *(const s16x8*)(Abl);     al1 = *(const s16x8*)(Abl + 8);
    }

    f32x4 acc[4][2];
    #pragma unroll
    for(int mt=0;mt<4;mt++){ acc[mt][0]=f32x4{0,0,0,0}; acc[mt][1]=f32x4{0,0,0,0}; }

    for(int kt=0;kt<24;kt++){
        #pragma unroll
        for(int s=0;s<8;s++){
            int k = sk + s*8;
            unsigned short hh[4], ll[4];
            #pragma unroll
            for(int e=0;e<4;e++){
                float w = wreg[s][e];
                hh[e] = bfrne(w); ll[e] = bfrne(w - bf2f(hh[e]));
            }
            *(unsigned*)(&Wh[k][sc])   = (unsigned)hh[0] | ((unsigned)hh[1]<<16);
            *(unsigned*)(&Wh[k][sc+2]) = (unsigned)hh[2] | ((unsigned)hh[3]<<16);
            *(unsigned*)(&Wl[k][sc])   = (unsigned)ll[0] | ((unsigned)ll[1]<<16);
            *(unsigned*)(&Wl[k][sc+2]) = (unsigned)ll[2] | ((unsigned)ll[3]<<16);
        }
        *(s16x8*)(&Ah[am][ac]) = ah0;  *(s16x8*)(&Ah[am][ac+8]) = ah1;
        *(s16x8*)(&Al[am][ac]) = al0;  *(s16x8*)(&Al[am][ac+8]) = al1;
        __syncthreads();
        if(kt < 23){
            int kn = kt+1;
            const float* Wb = (kn<8) ? (Wsb + (size_t)(kn*64)*DKT)
                                     : (W1b + (size_t)(kn*64-512)*DKT);
            #pragma unroll
            for(int s=0;s<8;s++)
                wreg[s] = *(const f32x4*)(Wb + (size_t)(sk + s*8)*DKT + n0 + sc);
            const unsigned short* Abh = Ahi + am*1536 + kn*64 + ac;
            const unsigned short* Abl = Alo + am*1536 + kn*64 + ac;
            ah0 = *(const s16x8*)(Abh);     ah1 = *(const s16x8*)(Abh + 8);
            al0 = *(const s16x8*)(Abl);     al1 = *(const s16x8*)(Abl + 8);
        }
        #pragma unroll
        for(int ks=0;ks<2;ks++){
            s16x8 afh[4], afl[4];
            #pragma unroll
            for(int mt=0;mt<4;mt++){
                afh[mt] = *(const s16x8*)(&Ah[mt*16+l15][ks*32+lkb]);
                afl[mt] = *(const s16x8*)(&Al[mt*16+l15][ks*32+lkb]);
            }
            #pragma unroll
            for(int nt=0;nt<2;nt++){
                int col = wv*32 + nt*16 + l15;
                FragU bh, bl;
                #pragma unroll
                for(int j=0;j<8;j++){
                    bh.h[j] = Wh[ks*32+lkb+j][col];
                    bl.h[j] = Wl[ks*32+lkb+j][col];
                }
                #pragma unroll
                for(int mt=0;mt<4;mt++){
                    acc[mt][nt] = mfma16(afh[mt], bh.v, acc[mt][nt]);
                    acc[mt][nt] = mfma16(afh[mt], bl.v, acc[mt][nt]);
                    acc[mt][nt] = mfma16(afl[mt], bh.v, acc[mt][nt]);
                }
            }
        }
        __syncthreads();
    }
    // epilogue: write frag-major (bitwise-identical values)
    #pragma unroll
    for(int nt=0;nt<2;nt++){
        int n = n0 + wv*32 + nt*16 + l15;
        float bias = bs[n] + 0.1f*b1[n];
        bool isW = (n < 110592);
        size_t colpart = 0; int nb2 = 0;
        if(isW){
            int L = n / 36864, rem = n - L*36864;
            int g = rem / 9216; int rem2 = rem - g*9216;
            int oo = rem2 / 96; int kk = rem2 - oo*96;
            int lane2 = (((kk&31)>>3)<<4) + (oo&15);
            int f = (oo>>4)*3 + (kk>>5);
            colpart = ((((size_t)(g*3 + L))*18 + f)*64 + lane2)*8 + (kk&7);
        } else nb2 = n - 110592;
        #pragma unroll
        for(int mt=0;mt<4;mt++)
            #pragma unroll
            for(int q=0;q<4;q++){
                int row = mt*16 + lg*4 + q;
                float v = acc[mt][nt][q] + bias;
                unsigned short hh = bfrne(v);
                if(isW){
                    size_t dst = (size_t)row*110592 + colpart;
                    KSfh[dst] = hh;
                    KSfl[dst] = bfrne(v - bf2f(hh));
                } else {
                    KSb32[(size_t)row*1152 + nb2] = v;
                }
            }
    }
}

// ---------------- stats v2: one block per (ch, b, SCALE); id stats in s==0 ----
// BITWISE-FROZEN: per-scale loops, per-thread sums, and blk_reduce2 order are
// identical to the fused version (s is block-uniform).
__global__ __launch_bounds__(256) void k_stat(const float* __restrict__ outPrev,
    float2* __restrict__ stats, float* __restrict__ gxy)
{
    __shared__ float img[4096], va[4096], vb[4096];
    __shared__ float ct[17], stp[17];
    __shared__ float red[8];
    int t = threadIdx.x, ch = blockIdx.x, b = blockIdx.y, s = blockIdx.z;
    const float* src = outPrev + ((size_t)b*32 + ch)*4096;
    float2* stc = stats + (b*32 + ch)*9;
    float* gb = gxy + ((size_t)(b*32 + ch)*8)*4096;
    for(int i=t;i<4096;i+=256) img[i] = src[i];
    __syncthreads();
    if(s == 0){
        float s0=0.f, s1=0.f;
        for(int i=t;i<4096;i+=256){ float v=img[i]; s0+=v; s1+=v*v; }
        blk_reduce2(s0, s1, red);
        float mu = s0*(1.f/4096.f);
        float var = s1*(1.f/4096.f) - mu*mu; var = var<0.f?0.f:var;
        if(t==0) stc[0] = make_float2(mu, rsqrtf(var + 1e-5f));
    }
    const int ksz[4] = {3,5,9,17};
    int k = ksz[s], p = (k-1)>>1;
    if(t < k){
        float cc = -1.f + 2.f*(float)t/(float)(k-1);
        ct[t]  = cosf(1.5707963267948966f*cc);
        stp[t] = sinf(1.5707963267948966f*cc);
    }
    __syncthreads();
    for(int i=t;i<4096;i+=256){
        int y = i>>6, x = i&63; float ac=0.f, as=0.f;
        for(int tt=0;tt<k;tt++){
            int yy = y+tt-p;
            if(yy>=0 && yy<64){ float f = img[yy*64+x]; ac += ct[tt]*f; as += stp[tt]*f; }
        }
        va[i]=ac; vb[i]=as;
    }
    __syncthreads();
    float gx0=0.f,gx1=0.f,gy0=0.f,gy1=0.f;
    float* g0 = gb + (size_t)(2*s)*4096;
    float* g1 = gb + (size_t)(2*s+1)*4096;
    for(int i=t;i<4096;i+=256){
        int y=i>>6, x=i&63; float gx=0.f, gy=0.f;
        for(int tt=0;tt<k;tt++){
            int xx = x+tt-p;
            if(xx>=0 && xx<64){ gx += stp[tt]*va[y*64+xx]; gy += ct[tt]*vb[y*64+xx]; }
        }
        g0[i] = gx; g1[i] = gy;
        gx0+=gx; gx1+=gx*gx; gy0+=gy; gy1+=gy*gy;
    }
    blk_reduce2(gx0, gx1, red);
    blk_reduce2(gy0, gy1, red);
    float mgx = gx0*(1.f/4096.f), vgx = gx1*(1.f/4096.f)-mgx*mgx; vgx=vgx<0.f?0.f:vgx;
    float mgy = gy0*(1.f/4096.f), vgy = gy1*(1.f/4096.f)-mgy*mgy; vgy=vgy<0.f?0.f:vgy;
    if(t==0){
        stc[1+2*s] = make_float2(mgx, rsqrtf(vgx+1e-5f));
        stc[2+2*s] = make_float2(mgy, rsqrtf(vgy+1e-5f));
    }
}

// ---------------- MEGA v5: ch-octet-major z LDS ------------------------------
__global__ __launch_bounds__(512) void k_mega(const float* __restrict__ outPrev,
    const float2* __restrict__ stats, const float* __restrict__ gxy,
    const unsigned short* __restrict__ KSfh, const unsigned short* __restrict__ KSfl,
    const float* __restrict__ KSb32,
    const unsigned short* __restrict__ w016, const unsigned short* __restrict__ w116,
    const unsigned short* __restrict__ wcsh, const unsigned short* __restrict__ wcsl,
    const float* __restrict__ c0b, const float* __restrict__ c1b,
    const float* __restrict__ csb,
    float* __restrict__ outNext, int cCall)
{
    __shared__ __align__(16) unsigned short zth[12][4][64][8];   // 48 KB
    __shared__ __align__(16) unsigned short ztl[12][4][64][8];   // 48 KB
    __shared__ __align__(16) unsigned short lhf[25600];          // 50 KB
    __shared__ float2 sst[288];
    int t = threadIdx.x, x = t&63, cq = t>>6;     // cq = wave 0..7
    int y = blockIdx.x, b = blockIdx.y;
    const float* ob = outPrev + (size_t)b*131072;
    for(int i=t;i<288;i+=512) sst[i] = stats[b*288 + i];
    __syncthreads();
    int qh = cq>>1, qo = (cq&1)*4;
    {
        U4 idh, idl;
        #pragma unroll
        for(int i=0;i<4;i++){
            int ch = cq*4 + i;
            float v = ob[(size_t)ch*4096 + y*64 + x];
            float2 sr = sst[ch*9];
            float z = (v - sr.x)*sr.y;
            idh.h[i] = bfrne(z); idl.h[i] = bfrne(z - bf2f(idh.h[i]));
        }
        #pragma unroll
        for(int s=0;s<4;s++){
            *(s16x4*)(&zth[3*s][qh][x][qo]) = idh.v;
            *(s16x4*)(&ztl[3*s][qh][x][qo]) = idl.v;
        }
    }
    #pragma unroll 1
    for(int s=0;s<4;s++){
        U4 xh, xl, yh, yl;
        #pragma unroll
        for(int i=0;i<4;i++){
            int ch = cq*4 + i;
            const float* gsrc = gxy + ((size_t)(b*32 + ch)*8)*4096 + y*64 + x;
            float gx = gsrc[(size_t)(2*s)*4096];
            float gy = gsrc[(size_t)(2*s+1)*4096];
            float2 sx = sst[ch*9 + 1+2*s], sy = sst[ch*9 + 2+2*s];
            float zx = (gx - sx.x)*sx.y, zy = (gy - sy.x)*sy.y;
            xh.h[i] = bfrne(zx); xl.h[i] = bfrne(zx - bf2f(xh.h[i]));
            yh.h[i] = bfrne(zy); yl.h[i] = bfrne(zy - bf2f(yh.h[i]));
        }
        *(s16x4*)(&zth[3*s+1][qh][x][qo]) = xh.v;
        *(s16x4*)(&ztl[3*s+1][qh][x][qo]) = xl.v;
        *(s16x4*)(&zth[3*s+2][qh][x][qo]) = yh.v;
        *(s16x4*)(&ztl[3*s+2][qh][x][qo]) = yl.v;
    }
    __syncthreads();

    int lane = t&63, l15 = lane&15, lg = lane>>4, lkb = lg*8, w = cq;
    int pxslot = w&3, half = w>>2;
    int row = cCall*8 + b;
    int pxl = pxslot*16 + l15;
    unsigned short* lhh = &lhf[w*3200];
    unsigned short* lhl = &lhf[w*3200 + 1600];
    #pragma unroll 1
    for(int gi=0; gi<2; gi++){
        int g = half*2 + gi;
        const unsigned short* Kfh = KSfh + (size_t)((row*4 + g)*3)*9216;
        const unsigned short* Kfl = KSfl + (size_t)((row*4 + g)*3)*9216;
        const float* Bf = KSb32 + (size_t)row*1152 + g*96;

        f32x4 acc[6];
        #pragma unroll
        for(int mt=0;mt<6;mt++) acc[mt]=f32x4{0,0,0,0};
        #pragma unroll
        for(int kt=0;kt<3;kt++){
            s16x8 bh = *(const s16x8*)(&zth[g*3+kt][lg][pxl][0]);
            s16x8 bl = *(const s16x8*)(&ztl[g*3+kt][lg][pxl][0]);
            #pragma unroll
            for(int mt=0;mt<6;mt++){
                s16x8 ah = *(const s16x8*)(Kfh + ((mt*3+kt)*64 + lane)*8);
                s16x8 al = *(const s16x8*)(Kfl + ((mt*3+kt)*64 + lane)*8);
                acc[mt] = mfma16(ah, bh, acc[mt]);
                acc[mt] = mfma16(ah, bl, acc[mt]);
                acc[mt] = mfma16(al, bh, acc[mt]);
            }
        }
        #pragma unroll
        for(int mt=0;mt<6;mt++){
            int o0 = mt*16 + lg*4;
            f32x4 bb = *(const f32x4*)(Bf + o0);
            U4 hh, hl;
            #pragma unroll
            for(int q=0;q<4;q++){
                float v = lrelu(acc[mt][q] + bb[q]);
                hh.h[q] = bfrne(v); hl.h[q] = bfrne(v - bf2f(hh.h[q]));
            }
            *(s16x4*)(&lhh[l15*100 + o0]) = hh.v;
            *(s16x4*)(&lhl[l15*100 + o0]) = hl.v;
        }
        #pragma unroll
        for(int mt=0;mt<6;mt++) acc[mt]=f32x4{0,0,0,0};
        #pragma unroll
        for(int kt=0;kt<3;kt++){
            s16x8 bh = *(const s16x8*)(&lhh[l15*100 + kt*32+lkb]);
            s16x8 bl = *(const s16x8*)(&lhl[l15*100 + kt*32+lkb]);
            #pragma unroll
            for(int mt=0;mt<6;mt++){
                s16x8 ah = *(const s16x8*)(Kfh + 9216 + ((mt*3+kt)*64 + lane)*8);
                s16x8 al = *(const s16x8*)(Kfl + 9216 + ((mt*3+kt)*64 + lane)*8);
                acc[mt] = mfma16(ah, bh, acc[mt]);
                acc[mt] = mfma16(ah, bl, acc[mt]);
                acc[mt] = mfma16(al, bh, acc[mt]);
            }
        }
        #pragma unroll
        for(int mt=0;mt<6;mt++){
            int o0 = mt*16 + lg*4;
            f32x4 bb = *(const f32x4*)(Bf + 384 + o0);
            U4 hh, hl;
            #pragma unroll
            for(int q=0;q<4;q++){
                float v = lrelu(acc[mt][q] + bb[q]);
                hh.h[q] = bfrne(v); hl.h[q] = bfrne(v - bf2f(hh.h[q]));
            }
            *(s16x4*)(&lhh[l15*100 + o0]) = hh.v;
            *(s16x4*)(&lhl[l15*100 + o0]) = hl.v;
        }
        #pragma unroll
        for(int mt=0;mt<6;mt++) acc[mt]=f32x4{0,0,0,0};
        #pragma unroll
        for(int kt=0;kt<3;kt++){
            s16x8 bh = *(const s16x8*)(&lhh[l15*100 + kt*32+lkb]);
            s16x8 bl = *(const s16x8*)(&lhl[l15*100 + kt*32+lkb]);
            #pragma unroll
            for(int mt=0;mt<6;mt++){
                s16x8 ah = *(const s16x8*)(Kfh + 18432 + ((mt*3+kt)*64 + lane)*8);
                s16x8 al = *(const s16x8*)(Kfl + 18432 + ((mt*3+kt)*64 + lane)*8);
                acc[mt] = mfma16(ah, bh, acc[mt]);
                acc[mt] = mfma16(ah, bl, acc[mt]);
                acc[mt] = mfma16(al, bh, acc[mt]);
            }
        }
        #pragma unroll
        for(int mt=0;mt<6;mt++){
            int o0 = mt*16 + lg*4;
            f32x4 bb = *(const f32x4*)(Bf + 768 + o0);
            int part = g*3 + (o0>>5), cc = o0&31;
            int q8 = cc>>3, off = cc&7;
            U4 zvh, zvl;
            zvh.v = *(const s16x4*)(&zth[part][q8][pxl][off]);
            zvl.v = *(const s16x4*)(&ztl[part][q8][pxl][off]);
            U4 ozh;
            #pragma unroll
            for(int q=0;q<4;q++){
                float zf = bf2f(zvh.h[q]) + bf2f(zvl.h[q]);
                float d  = zf + acc[mt][q] + bb[q];
                float sg = 1.f/(1.f + __expf(-d));
                ozh.h[q] = bfrne(zf*sg);
            }
            *(s16x4*)(&zth[part][q8][pxl][off]) = ozh.v;
        }
    }
    __syncthreads();

    unsigned short* ldx = &lhf[pxslot*6272];
    f32x4 a1[12];
    #pragma unroll
    for(int lm=0;lm<12;lm++) a1[lm]=f32x4{0,0,0,0};
    #pragma unroll 1
    for(int kt=0;kt<12;kt++){
        FragU bzh, blz;
        bzh.v = *(const s16x8*)(&zth[kt][lg][pxl][0]);
        #pragma unroll
        for(int j=0;j<8;j++) blz.h[j] = bfrne(lrelu(bf2f(bzh.h[j])));
        #pragma unroll
        for(int lm=0;lm<12;lm++){
            int mt = half*12 + lm;
            s16x8 af = *(const s16x8*)(w016 + ((size_t)(mt*12+kt)<<9) + (lane<<3));
            a1[lm] = mfma16(af, blz.v, a1[lm]);
        }
    }
    #pragma unroll
    for(int lm=0;lm<12;lm++){
        int mt = half*12 + lm;
        int o0 = mt*16 + lg*4;
        f32x4 bb = *(const f32x4*)(c0b + o0);
        U4 hv;
        #pragma unroll
        for(int q=0;q<4;q++) hv.h[q] = bfrne(lrelu(a1[lm][q] + bb[q]));
        *(s16x4*)(&ldx[l15*392 + o0]) = hv.v;
    }
    __syncthreads();

    {
        int mt = half;
        f32x4 a2 = f32x4{0,0,0,0};
        f32x4 a3 = f32x4{0,0,0,0};
        #pragma unroll 1
        for(int kt=0;kt<12;kt++){
            s16x8 bh_ = *(const s16x8*)(&ldx[l15*392 + kt*32 + lkb]);
            s16x8 bzh = *(const s16x8*)(&zth[kt][lg][pxl][0]);
            s16x8 af1 = *(const s16x8*)(w116 + ((size_t)(mt*12+kt)<<9) + (lane<<3));
            a2 = mfma16(af1, bh_, a2);
            s16x8 wh = *(const s16x8*)(wcsh + ((size_t)(mt*12+kt)<<9) + (lane<<3));
            s16x8 wl = *(const s16x8*)(wcsl + ((size_t)(mt*12+kt)<<9) + (lane<<3));
            a3 = mfma16(wh, bzh, a3);
            a3 = mfma16(wl, bzh, a3);
        }
        int o0 = mt*16 + lg*4;
        #pragma unroll
        for(int q=0;q<4;q++){
            int o = o0+q;
            int px = y*64 + pxl;
            float dx2 = a2[q] + c1b[o];
            float r   = a3[q] + csb[o] + 0.1f*dx2;
            size_t oidx = (size_t)b*131072 + (size_t)o*4096 + px;
            outNext[oidx] = outPrev[oidx] + 0.1f*r;
        }
    }
}

// ---------------- head ----------------
__global__ __launch_bounds__(256) void k_head1(const float* __restrict__ outF,
    const float* __restrict__ wout, const float* __restrict__ bout, float* __restrict__ state)
{
    __shared__ float sw[97*32];
    __shared__ float sb_[97];
    __shared__ float fp[32];
    __shared__ float fwp[2048];
    int t = threadIdx.x, b = blockIdx.y, pxb = blockIdx.x*256;
    for(int i=t;i<97*32;i+=256) sw[i] = wout[i];
    if(t<97) sb_[t] = bout[t];
    if(t<32) fp[t] = 0.f;
    for(int i=t;i<2048;i+=256) fwp[i] = 0.f;
    __syncthreads();
    int px = pxb + t, lane = t&63, wv = t>>6;
    float xi[32];
    #pragma unroll
    for(int i=0;i<32;i++) xi[i] = outF[(size_t)b*131072 + (size_t)i*4096 + px];
    float* st = state + (size_t)b*8224;
    int row = (pxb>>6) + wv, x = lane;
    for(int o=0;o<97;o++){
        float acc = sb_[o];
        #pragma unroll
        for(int i=0;i<32;i++) acc += sw[o*32+i]*xi[i];
        if(o < 32){
            float s = wave_sum(acc);
            if(lane==0) atomicAdd(&fp[o], s);
        } else if(o < 64){
            float s = wave_sum(acc);
            if(lane==0) st[32 + (o-32)*64 + row] = s*(1.f/64.f);
        } else if(o < 96){
            atomicAdd(&fwp[(o-64)*64 + x], acc);
        } else {
            st[4128 + px] = acc;
        }
    }
    __syncthreads();
    if(t<32) atomicAdd(&st[t], fp[t]*(1.f/4096.f));
    for(int i=t;i<2048;i+=256) atomicAdd(&st[2080+i], fwp[i]*(1.f/64.f));
}

__global__ __launch_bounds__(256) void k_head2(const float* __restrict__ state,
    const float* __restrict__ otlw, float* __restrict__ latout)
{
    __shared__ float ss[8*514];
    int t = threadIdx.x, j = blockIdx.x*256 + t, s0 = blockIdx.y*514;
    for(int i=t;i<8*514;i+=256){ int bb=i/514, si=i-bb*514; ss[i] = state[(size_t)bb*8224 + s0 + si]; }
    __syncthreads();
    float acc[8] = {0,0,0,0,0,0,0,0};
    for(int si=0;si<514;si++){
        float wv_ = otlw[(size_t)(s0+si)*512 + j];
        #pragma unroll
        for(int b2=0;b2<8;b2++) acc[b2] += ss[b2*514+si]*wv_;
    }
    #pragma unroll
    for(int b2=0;b2<8;b2++) atomicAdd(latout + b2*512 + j, acc[b2]);
}

// =============================================================================
extern "C" void kernel_launch(void* const* d_in, const int* in_sizes, int n_in,
                              void* d_out, int out_size, void* d_ws, size_t ws_size,
                              hipStream_t stream)
{
    const float* x    = (const float*)d_in[0];
    const float* inj  = (const float*)d_in[1];
    const float* icw  = (const float*)d_in[2];
    const float* icb  = (const float*)d_in[3];
    const float* flWs = (const float*)d_in[4];
    const float* flbs = (const float*)d_in[5];
    const float* flW0 = (const float*)d_in[6];
    const float* flb0 = (const float*)d_in[7];
    const float* flW1 = (const float*)d_in[8];
    const float* flb1 = (const float*)d_in[9];
    const float* dkWs = (const float*)d_in[10];
    const float* dkbs = (const float*)d_in[11];
    const float* dkW0 = (const float*)d_in[12];
    const float* dkb0 = (const float*)d_in[13];
    const float* dkW1 = (const float*)d_in[14];
    const float* dkb1 = (const float*)d_in[15];
    const float* c0w  = (const float*)d_in[16];
    const float* c0b  = (const float*)d_in[17];
    const float* c1w  = (const float*)d_in[18];
    const float* c1b  = (const float*)d_in[19];
    const float* csw  = (const float*)d_in[20];
    const float* csb  = (const float*)d_in[21];
    const float* ocw  = (const float*)d_in[22];
    const float* ocb  = (const float*)d_in[23];
    const float* otlw = (const float*)d_in[24];
    const float* otlb = (const float*)d_in[25];
    float* out = (float*)d_out;

    char* wp = (char*)d_ws;
    auto carve = [&](size_t bytes)->void*{ void* p = wp; wp += (bytes + 255) & ~(size_t)255; return p; };
    float* lats  = (float*)carve(36864*4);
    float* ppS   = (float*)carve(32768*4);
    float* ppH   = (float*)carve(32768*4);
    float* ppD   = (float*)carve(524288*4);
    float* state = (float*)carve(65792*4);
    float2* stats = (float2*)carve(2304*8);
    float* gxy   = (float*)carve((size_t)8388608*4);
    unsigned short* Ahi   = (unsigned short*)carve((size_t)98304*2);
    unsigned short* Alo   = (unsigned short*)carve((size_t)98304*2);
    unsigned short* KSfh  = (unsigned short*)carve((size_t)7077888*2);
    unsigned short* KSfl  = (unsigned short*)carve((size_t)7077888*2);
    float*          KSb32 = (float*)carve((size_t)73728*4);
    unsigned short* w016  = (unsigned short*)carve((size_t)147456*2);
    unsigned short* w116  = (unsigned short*)carve((size_t)12288*2);
    unsigned short* wcsh  = (unsigned short*)carve((size_t)12288*2);
    unsigned short* wcsl  = (unsigned short*)carve((size_t)12288*2);

    k_init<<<5105,256,0,stream>>>(state, out, otlb, lats, inj,
                                  w016, c0w, w116, c1w, wcsh, wcsl, csw,
                                  x, icw, icb, out + 4096);

    for(int c=0;c<8;c++){
        const float* latc = lats + c*4096;
        k_latA<<<dim3(4,4,2),256,0,stream>>>(latc, flWs + (size_t)c*262144, flW0 + (size_t)c*262144,
                                             ppS, ppH);
        k_latBC<<<4,256,0,stream>>>(ppH, flb0 + (size_t)c*512,
                                    flW1 + (size_t)c*262144, flb1 + (size_t)c*512,
                                    latc, ppS, flbs + (size_t)c*512, lats + (c+1)*4096);
    }

    k_dkH<<<dim3(8,4),256,0,stream>>>(lats + 4096, dkW0, ppD);
    k_dkAcvt<<<384,256,0,stream>>>(lats + 4096, ppD, dkb0, Ahi, Alo);
    k_dkMain<<<873,256,0,stream>>>(Ahi, Alo, dkWs, dkW1, dkbs, dkb1, KSfh, KSfl, KSb32);

    for(int c=0;c<8;c++){
        const float* outPrev = out + 4096 + (size_t)c*EMB;
        float*       outNext = out + 4096 + (size_t)(c+1)*EMB;
        k_stat<<<dim3(32,8,4),256,0,stream>>>(outPrev, stats, gxy);
        k_mega<<<dim3(64,8),512,0,stream>>>(outPrev, stats, gxy, KSfh, KSfl, KSb32,
                                            w016, w116, wcsh, wcsl,
                                            c0b, c1b, csb, outNext, c);
    }

    k_head1<<<dim3(16,8),256,0,stream>>>(out + 4096 + (size_t)8*EMB, ocw, ocb, state);
    k_head2<<<dim3(2,16),256,0,stream>>>(state, otlw, out);
}